// Round 10
// baseline (356.346 us; speedup 1.0000x reference)
//
#include <hip/hip_runtime.h>
#include <hip/hip_bf16.h>

#define M_TOK 8192
#define N_OUT 4096
#define K_IN  4096

typedef __attribute__((ext_vector_type(8))) short bf16x8;
typedef __attribute__((ext_vector_type(4))) float f32x4;
typedef unsigned short u16;

// fp32 -> bf16 RNE (finite inputs)
__device__ static inline u16 f2bf(float f) {
    union { float f; unsigned int u; } v; v.f = f;
    unsigned int u = v.u;
    u += 0x7FFFu + ((u >> 16) & 1u);
    return (u16)(u >> 16);
}

__device__ static inline void load_lds16(const void* g, void* l) {
    __builtin_amdgcn_global_load_lds(
        (const __attribute__((address_space(1))) unsigned int*)g,
        (__attribute__((address_space(3))) unsigned int*)l,
        16, 0, 0);
}

// ---------------- prep: x -> bf16 ; w -> fragment-packed bf16 -------------
// Packed layout (elems): pk[fc][kc][lane][e], fc=o>>4 (256), kc=i>>5 (128),
// lane=(o&15)|(((i>>3)&3)<<4), e=i&7.  Stride: fc 65536, kc 512, lane 8.
// GEMM reads 16B/lane fully coalesced (1 KB/wave per fragment).
__global__ void prep_kernel(const float* __restrict__ x,
                            const float* __restrict__ mean,
                            const float* __restrict__ sigma,
                            const float* __restrict__ noise,
                            const int* __restrict__ smult,
                            u16* __restrict__ xb, u16* __restrict__ wb) {
    if (blockIdx.x < 2048) {
        const int n4 = (M_TOK * K_IN) / 4;
        int i = blockIdx.x * blockDim.x + threadIdx.x;
        const int stride = 2048 * 256;
        for (int e = i; e < n4; e += stride) {
            float4 v = reinterpret_cast<const float4*>(x)[e];
            ushort4 o;
            o.x = f2bf(v.x); o.y = f2bf(v.y); o.z = f2bf(v.z); o.w = f2bf(v.w);
            reinterpret_cast<ushort4*>(xb)[e] = o;
        }
    } else {
        const float sm = (float)(*smult);
        const int NB8 = N_OUT * (K_IN / 8);               // o x i8 pairs
        int g = (blockIdx.x - 2048) * blockDim.x + threadIdx.x;
        const int stride = 1024 * 256;
        for (; g < NB8; g += stride) {
            const int o  = g >> 9;          // K_IN/8 = 512
            const int i8 = g & 511;
            const size_t src = (size_t)o * K_IN + (size_t)i8 * 8;
            float4 m0 = *reinterpret_cast<const float4*>(mean  + src);
            float4 m1 = *reinterpret_cast<const float4*>(mean  + src + 4);
            float4 s0 = *reinterpret_cast<const float4*>(sigma + src);
            float4 s1 = *reinterpret_cast<const float4*>(sigma + src + 4);
            float4 z0 = *reinterpret_cast<const float4*>(noise + src);
            float4 z1 = *reinterpret_cast<const float4*>(noise + src + 4);
            bf16x8 w;
            w[0] = (short)f2bf(m0.x * (1.0f + z0.x * fabsf(s0.x) * sm));
            w[1] = (short)f2bf(m0.y * (1.0f + z0.y * fabsf(s0.y) * sm));
            w[2] = (short)f2bf(m0.z * (1.0f + z0.z * fabsf(s0.z) * sm));
            w[3] = (short)f2bf(m0.w * (1.0f + z0.w * fabsf(s0.w) * sm));
            w[4] = (short)f2bf(m1.x * (1.0f + z1.x * fabsf(s1.x) * sm));
            w[5] = (short)f2bf(m1.y * (1.0f + z1.y * fabsf(s1.y) * sm));
            w[6] = (short)f2bf(m1.z * (1.0f + z1.z * fabsf(s1.z) * sm));
            w[7] = (short)f2bf(m1.w * (1.0f + z1.w * fabsf(s1.w) * sm));
            const size_t dst = (size_t)(o >> 4) * 65536 + (size_t)(i8 >> 2) * 512
                             + (size_t)((o & 15) | ((i8 & 3) << 4)) * 8;
            *reinterpret_cast<bf16x8*>(wb + dst) = w;
        }
    }
}

// ---- 256x256 GEMM: A via 4-deep LDS (32KB/tile), B global->reg (packed) ---
// C[t][o] = sum_k A[t][k]*B[o][k] + bias[o].
// LDS = 4 x 16384 elem (128 KiB), A only; barrier every 2 K-tiles; A staged
// 2 tiles ahead; B fragments loaded 1 tile ahead into 2 rotating reg sets.
// VMC(8) at window end drains A-stages only (B loads stay in flight).
// 16B-slot swizzle slot^=(row&7) on global src + ds_read (0 conflicts).

#define BARM()   { __builtin_amdgcn_s_barrier(); asm volatile("" ::: "memory"); }
#define SCHED0() __builtin_amdgcn_sched_barrier(0)
#define VMC8()   asm volatile("s_waitcnt vmcnt(8)" ::: "memory")

#define DS_A4(AR, AB) \
  _Pragma("unroll") for (int m_ = 0; m_ < 4; ++m_) { \
    AR[m_][0] = *reinterpret_cast<const bf16x8*>((AB) + m_*1024 + aoff0); \
    AR[m_][1] = *reinterpret_cast<const bf16x8*>((AB) + m_*1024 + aoff1); }

#define OCT8(MG, BS) \
  __builtin_amdgcn_s_setprio(1); \
  _Pragma("unroll") for (int m_ = 0; m_ < 4; ++m_) \
  _Pragma("unroll") for (int n_ = 0; n_ < 4; ++n_) { \
    acc[(MG)+m_][n_] = __builtin_amdgcn_mfma_f32_16x16x32_bf16( \
        aR[m_][0], BS[n_][0], acc[(MG)+m_][n_], 0, 0, 0); \
    acc[(MG)+m_][n_] = __builtin_amdgcn_mfma_f32_16x16x32_bf16( \
        aR[m_][1], BS[n_][1], acc[(MG)+m_][n_], 0, 0, 0); } \
  __builtin_amdgcn_s_setprio(0);

// stage full 256x64 A-tile (32 KB): rows q*64 + tid/8, 4 x gload_lds
#define STAGE_A(T, BUF) { \
  const u16* g_ = Abase + (size_t)srow * K_IN + (T)*64 + sxcol; \
  load_lds16(g_,                     smem + (BUF)*16384 +         tid*8); \
  load_lds16(g_ + (size_t) 64*K_IN,  smem + (BUF)*16384 +  4096 + tid*8); \
  load_lds16(g_ + (size_t)128*K_IN,  smem + (BUF)*16384 +  8192 + tid*8); \
  load_lds16(g_ + (size_t)192*K_IN,  smem + (BUF)*16384 + 12288 + tid*8); }

// B fragment loads from packed layout: 8 x dwordx4, coalesced per wave
#define LDBG(DST, T) \
  _Pragma("unroll") for (int n_ = 0; n_ < 4; ++n_) \
  _Pragma("unroll") for (int k_ = 0; k_ < 2; ++k_) \
    DST[n_][k_] = *reinterpret_cast<const bf16x8*>( \
        Bpk + (size_t)n_ * 65536 + (size_t)(T) * 1024 + k_ * 512);

// compute one K-tile from A-buf RB with B reg set BS (64 MFMA)
#define CTILE(RB, BS) { \
  const u16* A_ = smem + (RB)*16384 + wm*8192; \
  DS_A4(aR, A_); \
  OCT8(0, BS); \
  DS_A4(aR, A_ + 4096); \
  OCT8(4, BS); }

// window = 2 K-tiles (T0, T0+1): stage A(T0+2),A(T0+3); B 1 tile ahead
#define WINDOW(T0, RB0, RB1, WB0, WB1) { \
  const int t2_ = ((T0)+2 < 64) ? (T0)+2 : 63; \
  const int t3_ = ((T0)+3 < 64) ? (T0)+3 : 63; \
  const int tb1_ = ((T0)+1 < 64) ? (T0)+1 : 63; \
  STAGE_A(t2_, WB0); STAGE_A(t3_, WB1); \
  LDBG(bB, tb1_); \
  CTILE(RB0, bA); \
  SCHED0(); \
  LDBG(bA, t2_); \
  CTILE(RB1, bB); \
  VMC8(); BARM(); }

__global__ __launch_bounds__(512, 2)
void gemm_bias_kernel(const u16* __restrict__ A, const u16* __restrict__ Bp,
                      const float* __restrict__ bias, float* __restrict__ C) {
    __shared__ u16 smem[65536];   // 4 x 32 KiB A buffers

    const int tid   = threadIdx.x;
    const int lane  = tid & 63;
    const int wid   = tid >> 6;
    const int wm    = wid >> 2;      // 0..1  (M half, 128 rows)
    const int wn    = wid & 3;       // 0..3  (N slice, 64 cols)
    const int la_lo = lane & 15;
    const int la_hi = lane >> 4;

    // T1 v2: per-XCD 2D rectangle (kept from round 3)
    const int bid = blockIdx.x;
    const int xcd = bid & 7;
    const int c   = bid >> 3;
    const int r   = c >> 5;
    const int s   = c & 31;
    const int bm  = xcd * 4 + (s & 3);
    const int bn  = r * 8 + (s >> 2);
    const int brow = bm * 256;
    const int bcol = bn * 256;

    const u16* Abase = A + (size_t)brow * K_IN;
    // packed-B per-lane base: fragments fc = bn*16 + wn*4 + n_
    const u16* Bpk = Bp + (size_t)(bn * 16 + wn * 4) * 65536 + (size_t)lane * 8;

    // A staging swizzle (0 conflicts): row q*64+srow, slot = (tid&7)^(row&7)
    const int srow  = tid >> 3;
    const int sxcol = ((tid & 7) ^ (srow & 7)) * 8;

    // A ds_read swizzled offsets (0 conflicts)
    const int xorr  = la_lo & 7;
    const int aoff0 = la_lo * 64 + ((la_hi    ) ^ xorr) * 8;
    const int aoff1 = la_lo * 64 + ((la_hi + 4) ^ xorr) * 8;

    f32x4 acc[8][4];
    #pragma unroll
    for (int m = 0; m < 8; ++m)
        #pragma unroll
        for (int n = 0; n < 4; ++n)
            acc[m][n] = (f32x4){0.f, 0.f, 0.f, 0.f};

    bf16x8 aR[4][2];
    bf16x8 bA[4][2], bB[4][2];

    // Prologue: stage A(0)->buf0, A(1)->buf1; load B(0); drain A; barrier.
    STAGE_A(0, 0); STAGE_A(1, 1);
    LDBG(bA, 0);
    VMC8(); BARM();

    // 32 windows (64 K-tiles); x2 unroll for static buffer indices.
    for (int i = 0; i < 16; ++i) {
        WINDOW(4 * i,     0, 1, 2, 3);
        WINDOW(4 * i + 2, 2, 3, 0, 1);
    }

    // Epilogue: C/D layout col = lane&15, row = (lane>>4)*4 + rr; add bias
    const int crow0 = brow + wm * 128;
    const int ccol0 = bcol + wn * 64;
    #pragma unroll
    for (int n = 0; n < 4; ++n) {
        const int col = ccol0 + n * 16 + la_lo;
        const float bv = bias[col];
        #pragma unroll
        for (int m = 0; m < 8; ++m) {
            #pragma unroll
            for (int rr = 0; rr < 4; ++rr) {
                const int row = crow0 + m * 16 + la_hi * 4 + rr;
                C[(size_t)row * N_OUT + col] = acc[m][n][rr] + bv;
            }
        }
    }
}

extern "C" void kernel_launch(void* const* d_in, const int* in_sizes, int n_in,
                              void* d_out, int out_size, void* d_ws, size_t ws_size,
                              hipStream_t stream) {
    const float* x     = (const float*)d_in[0];
    const float* mean  = (const float*)d_in[1];
    const float* sigma = (const float*)d_in[2];
    const float* bias  = (const float*)d_in[3];
    const float* noise = (const float*)d_in[4];
    const int*   smult = (const int*)d_in[5];
    float* out = (float*)d_out;

    const size_t x_elems = (size_t)M_TOK * K_IN;
    const size_t w_elems = (size_t)N_OUT * K_IN;
    const size_t need = (x_elems + w_elems) * sizeof(u16);
    if (ws_size < need) return;

    u16* xb = (u16*)d_ws;
    u16* wb = xb + x_elems;

    prep_kernel<<<3072, 256, 0, stream>>>(x, mean, sigma, noise, smult, xb, wb);
    gemm_bias_kernel<<<512, 512, 0, stream>>>(xb, wb, bias, out);
}

// Round 11
// 341.194 us; speedup vs baseline: 1.0444x; 1.0444x over previous
//
#include <hip/hip_runtime.h>
#include <hip/hip_bf16.h>

#define M_TOK 8192
#define N_OUT 4096
#define K_IN  4096

typedef __attribute__((ext_vector_type(8))) short bf16x8;
typedef __attribute__((ext_vector_type(16))) float f32x16;
typedef unsigned short u16;

// fp32 -> bf16 RNE (finite inputs)
__device__ static inline u16 f2bf(float f) {
    union { float f; unsigned int u; } v; v.f = f;
    unsigned int u = v.u;
    u += 0x7FFFu + ((u >> 16) & 1u);
    return (u16)(u >> 16);
}

__device__ static inline void load_lds16(const void* g, void* l) {
    __builtin_amdgcn_global_load_lds(
        (const __attribute__((address_space(1))) unsigned int*)g,
        (__attribute__((address_space(3))) unsigned int*)l,
        16, 0, 0);
}

// ---------------- fused prep pass (memory-bound, ~HBM roofline) -----------
__global__ void prep_kernel(const float* __restrict__ x,
                            const float* __restrict__ mean,
                            const float* __restrict__ sigma,
                            const float* __restrict__ noise,
                            const int* __restrict__ smult,
                            u16* __restrict__ xb, u16* __restrict__ wb) {
    if (blockIdx.x < 2048) {
        const int n4 = (M_TOK * K_IN) / 4;
        int i = blockIdx.x * blockDim.x + threadIdx.x;
        const int stride = 2048 * 256;
        for (int e = i; e < n4; e += stride) {
            float4 v = reinterpret_cast<const float4*>(x)[e];
            ushort4 o;
            o.x = f2bf(v.x); o.y = f2bf(v.y); o.z = f2bf(v.z); o.w = f2bf(v.w);
            reinterpret_cast<ushort4*>(xb)[e] = o;
        }
    } else {
        const float sm = (float)(*smult);
        const int n4 = (N_OUT * K_IN) / 4;
        int i = (blockIdx.x - 2048) * blockDim.x + threadIdx.x;
        const int stride = 1024 * 256;
        for (int e = i; e < n4; e += stride) {
            float4 m = reinterpret_cast<const float4*>(mean)[e];
            float4 s = reinterpret_cast<const float4*>(sigma)[e];
            float4 z = reinterpret_cast<const float4*>(noise)[e];
            ushort4 o;
            o.x = f2bf(m.x * (1.0f + z.x * fabsf(s.x) * sm));
            o.y = f2bf(m.y * (1.0f + z.y * fabsf(s.y) * sm));
            o.z = f2bf(m.z * (1.0f + z.z * fabsf(s.z) * sm));
            o.w = f2bf(m.w * (1.0f + z.w * fabsf(s.w) * sm));
            reinterpret_cast<ushort4*>(wb)[e] = o;
        }
    }
}

// ------ 256x256 GEMM, round-8 skeleton (1 barrier/K-tile), 32x32x16 MFMA --
// C[t][o] = sum_k A[t][k]*B[o][k] + bias[o]; A=[M][K] bf16, B=[N][K] bf16.
// LDS: [buf(2)][A 16384 | B 16384 elem] = 128 KiB. 16B-slot swizzle
// slot^=(row&7) on global src of global_load_lds + on ds_read.
// Per K-tile: { 8 stage loads (t+1 -> buf^1) ; SCHED0 ; 24 ds_reads + 32
// MFMA(32x32x16) compiler-interleaved ; vmcnt(0) ; barrier }.
// Only change vs round 8 (248us): MFMA shape 16x16x32 -> 32x32x16
// (floor 2483 -> 2066 cyc/tile, half the MFMA instructions).

#define BARM()   { __builtin_amdgcn_s_barrier(); asm volatile("" ::: "memory"); }
#define SCHED0() __builtin_amdgcn_sched_barrier(0)
#define VMC0()   asm volatile("s_waitcnt vmcnt(0)" ::: "memory")

// A fragments for mt pair PAIR (rows PAIR*64 + mt_*32 + r31), kc=0..3
#define DS_A8(PAIR, AB) \
  _Pragma("unroll") for (int mt_ = 0; mt_ < 2; ++mt_) \
  _Pragma("unroll") for (int kc_ = 0; kc_ < 4; ++kc_) \
    aR[mt_][kc_] = *reinterpret_cast<const bf16x8*>( \
        (AB) + ((PAIR)*64 + mt_*32 + r31)*64 + koff[kc_]);

// B fragments for nt tile NT (rows NT*32 + r31), kc=0..3
#define DS_B4(NT, BB) \
  _Pragma("unroll") for (int kc_ = 0; kc_ < 4; ++kc_) \
    bR[NT][kc_] = *reinterpret_cast<const bf16x8*>( \
        (BB) + ((NT)*32 + r31)*64 + koff[kc_]);

// 16 MFMA: mt pair PAIR x nt(2) x kc(4); kc outer -> 4 independent chains
#define MX16(PAIR) \
  __builtin_amdgcn_s_setprio(1); \
  _Pragma("unroll") for (int kc_ = 0; kc_ < 4; ++kc_) \
  _Pragma("unroll") for (int mt_ = 0; mt_ < 2; ++mt_) \
  _Pragma("unroll") for (int nt_ = 0; nt_ < 2; ++nt_) \
    acc[(PAIR)*2 + mt_][nt_] = __builtin_amdgcn_mfma_f32_32x32x16_bf16( \
        aR[mt_][kc_], bR[nt_][kc_], acc[(PAIR)*2 + mt_][nt_], 0, 0, 0); \
  __builtin_amdgcn_s_setprio(0);

#define STAGE_A(T, H, BUF) { \
  const u16* g_ = Abase + (size_t)((H)*128 + srow) * K_IN + (T)*64 + sxcol; \
  load_lds16(g_, smem + (BUF)*32768 + (H)*8192 + tid*8); \
  load_lds16(g_ + (size_t)64*K_IN, smem + (BUF)*32768 + (H)*8192 + 4096 + tid*8); }

#define STAGE_B(T, H, BUF) { \
  const u16* g_ = Bbase + (size_t)((H)*128 + srow) * K_IN + (T)*64 + sxcol; \
  load_lds16(g_, smem + (BUF)*32768 + 16384 + (H)*8192 + tid*8); \
  load_lds16(g_ + (size_t)64*K_IN, smem + (BUF)*32768 + 16384 + (H)*8192 + 4096 + tid*8); }

// One K-tile: stage t+1 -> WB, read RB, 32 MFMA, gate, barrier.
#define TILE(T, RB, WB) { \
  const int tn_ = ((T) < 63) ? (T) + 1 : 63; \
  STAGE_A(tn_, 0, WB); STAGE_A(tn_, 1, WB); \
  STAGE_B(tn_, 0, WB); STAGE_B(tn_, 1, WB); \
  SCHED0(); \
  const u16* A_ = smem + (RB)*32768 + wm*8192; \
  const u16* B_ = smem + (RB)*32768 + 16384 + wn*4096; \
  DS_A8(0, A_); DS_B4(0, B_); DS_B4(1, B_); \
  MX16(0); \
  DS_A8(1, A_); \
  MX16(1); \
  VMC0(); BARM(); }

__global__ __launch_bounds__(512, 2)
void gemm_bias_kernel(const u16* __restrict__ A, const u16* __restrict__ B,
                      const float* __restrict__ bias, float* __restrict__ C) {
    __shared__ u16 smem[65536];   // 128 KiB

    const int tid  = threadIdx.x;
    const int lane = tid & 63;
    const int wid  = tid >> 6;
    const int wm   = wid >> 2;       // 0..1  (M half, 128 rows)
    const int wn   = wid & 3;        // 0..3  (N slice, 64 cols)
    const int r31  = lane & 31;
    const int hi5  = lane >> 5;

    // T1 v2: per-XCD 2D rectangle (FETCH 197 MB measured, keep)
    const int bid = blockIdx.x;
    const int xcd = bid & 7;
    const int c   = bid >> 3;
    const int r   = c >> 5;
    const int s   = c & 31;
    const int bm  = xcd * 4 + (s & 3);
    const int bn  = r * 8 + (s >> 2);
    const int brow = bm * 256;
    const int bcol = bn * 256;

    const u16* Abase = A + (size_t)brow * K_IN;
    const u16* Bbase = B + (size_t)bcol * K_IN;

    // staging swizzle (measured 0 conflicts)
    const int srow  = tid >> 3;
    const int sxcol = ((tid & 7) ^ (srow & 7)) * 8;

    // ds_read swizzled k-slot offsets (elements): slot = (kc*2+hi5)^(row&7)
    int koff[4];
    #pragma unroll
    for (int kc = 0; kc < 4; ++kc)
        koff[kc] = ((kc * 2 + hi5) ^ (r31 & 7)) * 8;

    f32x16 acc[4][2];
    #pragma unroll
    for (int m = 0; m < 4; ++m)
        #pragma unroll
        for (int n = 0; n < 2; ++n)
            #pragma unroll
            for (int e = 0; e < 16; ++e)
                acc[m][n][e] = 0.f;

    bf16x8 aR[2][4], bR[2][4];

    // Prologue: stage tile0 -> buf0 fully; drain; barrier.
    STAGE_A(0, 0, 0); STAGE_A(0, 1, 0);
    STAGE_B(0, 0, 0); STAGE_B(0, 1, 0);
    VMC0(); BARM();

    // 64 K-tiles, unrolled x2 for static buffer alternation.
    for (int i = 0; i < 32; ++i) {
        TILE(2 * i,     0, 1);
        TILE(2 * i + 1, 1, 0);
    }

    // Epilogue (round-4-verified 32x32 C/D mapping):
    // col = lane&31, row = (reg&3) + 8*(reg>>2) + 4*(lane>>5)
    const int crow0 = brow + wm * 128;
    const int ccol0 = bcol + wn * 64;
    #pragma unroll
    for (int nt = 0; nt < 2; ++nt) {
        const int col = ccol0 + nt * 32 + r31;
        const float bv = bias[col];
        #pragma unroll
        for (int mt = 0; mt < 4; ++mt) {
            #pragma unroll
            for (int g = 0; g < 4; ++g) {
                #pragma unroll
                for (int rr = 0; rr < 4; ++rr) {
                    const int row = crow0 + mt * 32 + g * 8 + 4 * hi5 + rr;
                    C[(size_t)row * N_OUT + col] = acc[mt][nt][g * 4 + rr] + bv;
                }
            }
        }
    }
}

extern "C" void kernel_launch(void* const* d_in, const int* in_sizes, int n_in,
                              void* d_out, int out_size, void* d_ws, size_t ws_size,
                              hipStream_t stream) {
    const float* x     = (const float*)d_in[0];
    const float* mean  = (const float*)d_in[1];
    const float* sigma = (const float*)d_in[2];
    const float* bias  = (const float*)d_in[3];
    const float* noise = (const float*)d_in[4];
    const int*   smult = (const int*)d_in[5];
    float* out = (float*)d_out;

    const size_t x_elems = (size_t)M_TOK * K_IN;
    const size_t w_elems = (size_t)N_OUT * K_IN;
    const size_t need = (x_elems + w_elems) * sizeof(u16);
    if (ws_size < need) return;

    u16* xb = (u16*)d_ws;
    u16* wb = xb + x_elems;

    prep_kernel<<<3072, 256, 0, stream>>>(x, mean, sigma, noise, smult, xb, wb);
    gemm_bias_kernel<<<512, 512, 0, stream>>>(xb, wb, bias, out);
}